// Round 2
// baseline (816.283 us; speedup 1.0000x reference)
//
#include <hip/hip_runtime.h>
#include <math.h>

#define DEVINL __device__ __forceinline__

// ---------------------------------------------------------------------------
// SplineCNN net. Round 1: binned (counting-sorted by kernel index) spline conv
// so W_k is staged in LDS and reused across a 64-row tile -> GEMM-shaped.
// ---------------------------------------------------------------------------

// Monotone mapping: float -> unsigned preserving order, so atomicMax works.
DEVINL unsigned f2mono(float f) {
    unsigned u = __float_as_uint(f);
    return (u & 0x80000000u) ? ~u : (u | 0x80000000u);
}
DEVINL float mono2f(unsigned m) {
    unsigned u = (m & 0x80000000u) ? (m & 0x7FFFFFFFu) : ~m;
    return __uint_as_float(u);
}

__global__ void fill_u32(unsigned* __restrict__ p, int n, unsigned v) {
    int i = blockIdx.x * blockDim.x + threadIdx.x;
    if (i < n) p[i] = v;
}

// scatter max: x [n_in, C] -> mono [n_out, C] via cluster ids
__global__ void pool_scatter(const float* __restrict__ x, const int* __restrict__ cl,
                             unsigned* __restrict__ mono, int n_in, int C) {
    int i = blockIdx.x * blockDim.x + threadIdx.x;
    if (i >= n_in * C) return;
    int node = i / C;
    int c = i - node * C;
    atomicMax(&mono[cl[node] * C + c], f2mono(x[i]));
}

__global__ void pool_final(const unsigned* __restrict__ mono, float* __restrict__ out, int n) {
    int i = blockIdx.x * blockDim.x + threadIdx.x;
    if (i < n) {
        unsigned m = mono[i];
        out[i] = (m == 0u) ? 0.f : mono2f(m);  // sentinel 0 == empty segment
    }
}

DEVINL void pseudo_decode(const float* __restrict__ ps, int e, int ff[3], float fr[3]) {
#pragma unroll
    for (int d = 0; d < 3; ++d) {
        float p = ps[(size_t)e * 3 + d] * 4.0f;  // (K-1) = 4
        float f = floorf(p);
        ff[d] = (int)f;
        fr[d] = p - f;
    }
}

DEVINL void corner_iw(const int ff[3], const float fr[3], int bits, float& w, int& idx) {
    w = 1.f;
    idx = 0;
    int pw = 1;
#pragma unroll
    for (int d = 0; d < 3; ++d) {
        int b = (bits >> d) & 1;
        w *= b ? fr[d] : (1.f - fr[d]);
        int fd = ff[d] + b;
        fd = fd < 0 ? 0 : (fd > 4 ? 4 : fd);
        idx += fd * pw;
        pw *= 5;
    }
}

// ---------------- level 1 (Cin=1, Cout=32): direct edge kernel ----------------
__global__ void spline_edge_c1(const float* __restrict__ x, const int* __restrict__ src,
                               const int* __restrict__ dst, const float* __restrict__ pseudo,
                               const float* __restrict__ W, float* __restrict__ agg,
                               float* __restrict__ deg, int E) {
    int tid = blockIdx.x * 256 + threadIdx.x;
    int e = tid >> 5;
    int c = tid & 31;
    if (e >= E) return;
    int ff[3];
    float fr[3];
    pseudo_decode(pseudo, e, ff, fr);
    float acc = 0.f;
#pragma unroll
    for (int b = 0; b < 8; ++b) {
        float w;
        int idx;
        corner_iw(ff, fr, b, w, idx);
        acc += w * W[idx * 32 + c];
    }
    int d = dst[e];
    atomicAdd(&agg[(size_t)d * 32 + c], x[src[e]] * acc);
    if (c == 0) atomicAdd(&deg[d], 1.f);
}

// ---------------- binned path (levels 2-5) ----------------
__global__ void hist_deg_kernel(const float* __restrict__ pseudo, const int* __restrict__ dst,
                                int E, int* __restrict__ hist, float* __restrict__ deg) {
    __shared__ int lh[125];
    int t = threadIdx.x;
    for (int i = t; i < 125; i += 256) lh[i] = 0;
    __syncthreads();
    int e = blockIdx.x * 256 + t;
    if (e < E) {
        int ff[3];
        float fr[3];
        pseudo_decode(pseudo, e, ff, fr);
#pragma unroll
        for (int b = 0; b < 8; ++b) {
            float w;
            int idx;
            corner_iw(ff, fr, b, w, idx);
            atomicAdd(&lh[idx], 1);
        }
        atomicAdd(&deg[dst[e]], 1.f);
    }
    __syncthreads();
    for (int i = t; i < 125; i += 256)
        if (lh[i]) atomicAdd(&hist[i], lh[i]);
}

template <int TM>
__global__ void prefix_tiles(const int* __restrict__ hist, int* __restrict__ binstart,
                             int* __restrict__ cursor, int* __restrict__ tile_k,
                             int* __restrict__ tile_lo, int* __restrict__ ntiles_p) {
    __shared__ int bs[126], ts[126];
    int t = threadIdx.x;
    if (t == 0) {
        int run = 0, trun = 0;
        for (int k = 0; k < 125; ++k) {
            bs[k] = run;
            ts[k] = trun;
            run += hist[k];
            trun += (hist[k] + TM - 1) / TM;
        }
        bs[125] = run;
        ts[125] = trun;
        *ntiles_p = trun;
    }
    __syncthreads();
    if (t < 126) binstart[t] = bs[t];
    if (t < 125) {
        cursor[t] = bs[t];
        int nt = ts[t + 1] - ts[t];
        for (int j = 0; j < nt; ++j) {
            tile_k[ts[t] + j] = t;
            tile_lo[ts[t] + j] = bs[t] + j * TM;
        }
    }
}

__global__ void scatter_kernel(const float* __restrict__ pseudo, const int* __restrict__ src,
                               const int* __restrict__ dst, int E, int* __restrict__ cursor,
                               float* __restrict__ sw, int* __restrict__ ssrc,
                               int* __restrict__ sdst) {
    __shared__ int lh[125], lbase[125];
    int t = threadIdx.x;
    for (int i = t; i < 125; i += 256) lh[i] = 0;
    __syncthreads();
    int e = blockIdx.x * 256 + t;
    int midx[8], mloc[8];
    float mw[8];
    if (e < E) {
        int ff[3];
        float fr[3];
        pseudo_decode(pseudo, e, ff, fr);
#pragma unroll
        for (int b = 0; b < 8; ++b) {
            corner_iw(ff, fr, b, mw[b], midx[b]);
            mloc[b] = atomicAdd(&lh[midx[b]], 1);
        }
    }
    __syncthreads();
    for (int i = t; i < 125; i += 256) {
        int c = lh[i];
        lbase[i] = c ? atomicAdd(&cursor[i], c) : 0;
    }
    __syncthreads();
    if (e < E) {
        int s = src[e], d = dst[e];
#pragma unroll
        for (int b = 0; b < 8; ++b) {
            int pos = lbase[midx[b]] + mloc[b];
            sw[pos] = mw[b];
            ssrc[pos] = s;
            sdst[pos] = d;
        }
    }
}

// One 64-row tile of one bin per loop iteration: W_k staged in LDS (reused 64x),
// w-scaled x rows staged in LDS, register-tiled fp32 GEMM, atomicAdd to agg[dst].
template <int CIN, int COUT, int TM>
__global__ __launch_bounds__(256) void bin_gemm(
    const float* __restrict__ x, const float* __restrict__ W, const float* __restrict__ sw,
    const int* __restrict__ ssrc, const int* __restrict__ sdst, const int* __restrict__ tile_k,
    const int* __restrict__ tile_lo, const int* __restrict__ binstart,
    const int* __restrict__ ntiles_p, float* __restrict__ agg) {
    constexpr int C4 = COUT / 4;   // float4 column groups
    constexpr int NTR = 256 / C4;  // row-thread groups
    constexpr int RT = TM / NTR;   // rows per thread
    constexpr int XST = CIN + 4;   // padded x row stride (keeps float4 align, breaks banks)
    constexpr int G = 256 / TM;    // threads per staged row
    __shared__ float Wl[CIN * COUT];
    __shared__ float xs[TM * XST];
    __shared__ int dl[TM];
    int t = threadIdx.x;
    int ntiles = *ntiles_p;
    int tc = t % C4, tr = t / C4;
    int rr = t / G, g = t % G;
    for (int tile = blockIdx.x; tile < ntiles; tile += gridDim.x) {
        int k = tile_k[tile];
        int lo = tile_lo[tile];
        int m = min(TM, binstart[k + 1] - lo);
        __syncthreads();  // previous iteration's readers done before restaging
        {
            const float4* Wg = (const float4*)(W + (size_t)k * (CIN * COUT));
            float4* Wl4 = (float4*)Wl;
            for (int i = t; i < CIN * COUT / 4; i += 256) Wl4[i] = Wg[i];
        }
        if (rr < m) {
            int s = ssrc[lo + rr];
            float wv = sw[lo + rr];
            if (g == 0) dl[rr] = sdst[lo + rr];
            const float4* xr = (const float4*)(x + (size_t)s * CIN);
            float4* xd = (float4*)(xs + rr * XST);
#pragma unroll
            for (int i = g; i < CIN / 4; i += G) {
                float4 v = xr[i];
                v.x *= wv;
                v.y *= wv;
                v.z *= wv;
                v.w *= wv;
                xd[i] = v;
            }
        }
        __syncthreads();
        float4 acc[RT];
#pragma unroll
        for (int r = 0; r < RT; ++r) acc[r] = make_float4(0.f, 0.f, 0.f, 0.f);
#pragma unroll 4
        for (int i = 0; i < CIN; ++i) {
            float4 wv = ((const float4*)Wl)[i * C4 + tc];
#pragma unroll
            for (int r = 0; r < RT; ++r) {
                float xv = xs[(tr + r * NTR) * XST + i];
                acc[r].x += xv * wv.x;
                acc[r].y += xv * wv.y;
                acc[r].z += xv * wv.z;
                acc[r].w += xv * wv.w;
            }
        }
#pragma unroll
        for (int r = 0; r < RT; ++r) {
            int row = tr + r * NTR;
            if (row < m) {
                float* ap = agg + (size_t)dl[row] * COUT + tc * 4;
                atomicAdd(ap + 0, acc[r].x);
                atomicAdd(ap + 1, acc[r].y);
                atomicAdd(ap + 2, acc[r].z);
                atomicAdd(ap + 3, acc[r].w);
            }
        }
    }
}

// y = elu(agg/max(deg,1) + x@root + bias)
template <int CIN, int COUT>
__global__ void conv_finish(const float* __restrict__ x, const float* __restrict__ agg,
                            const float* __restrict__ deg, const float* __restrict__ root,
                            const float* __restrict__ bias, float* __restrict__ y, int N) {
    int tid = blockIdx.x * blockDim.x + threadIdx.x;
    if (tid >= N * COUT) return;
    int n = tid / COUT;
    int c = tid - n * COUT;
    float d = deg[n];
    d = d > 1.f ? d : 1.f;
    float v = agg[tid] / d;
#pragma unroll
    for (int i = 0; i < CIN; ++i) v += x[(size_t)n * CIN + i] * root[(size_t)i * COUT + c];
    v += bias[c];
    y[tid] = v > 0.f ? v : expm1f(v);
}

// fc1: [1024] @ [1024,512] + b, ELU
__global__ void fc1_kernel(const float* __restrict__ x, const float* __restrict__ w,
                           const float* __restrict__ b, float* __restrict__ out) {
    int o = blockIdx.x * blockDim.x + threadIdx.x;
    if (o >= 512) return;
    float acc = b[o];
#pragma unroll 8
    for (int i = 0; i < 1024; ++i) acc += x[i] * w[(size_t)i * 512 + o];
    out[o] = acc > 0.f ? acc : expm1f(acc);
}

// fc2 (512->10) + log_softmax, single small block
__global__ void fc2_lsm(const float* __restrict__ x, const float* __restrict__ w,
                        const float* __restrict__ b, float* __restrict__ out) {
    __shared__ float z[10];
    int t = threadIdx.x;
    if (t < 10) {
        float acc = b[t];
        for (int i = 0; i < 512; ++i) acc += x[i] * w[(size_t)i * 10 + t];
        z[t] = acc;
    }
    __syncthreads();
    if (t == 0) {
        float m = z[0];
        for (int i = 1; i < 10; ++i) m = fmaxf(m, z[i]);
        float s = 0.f;
        for (int i = 0; i < 10; ++i) s += expf(z[i] - m);
        float l = logf(s);
        for (int i = 0; i < 10; ++i) out[i] = z[i] - m - l;
    }
}

// ---------------------------------------------------------------------------

template <int CIN, int COUT>
static void run_conv_binned(const float* x, const int* src, const int* dst, const float* ps,
                            const float* W, const float* root, const float* bias, float* y,
                            float* arena, int N, int E, hipStream_t stream) {
    constexpr int TM = 64;
    float* agg = arena;                    // N*COUT
    float* deg = agg + (size_t)N * COUT;   // N
    int* hist = (int*)(deg + N);           // 125
    int* binstart = hist + 125;            // 126
    int* cursor = binstart + 126;          // 125
    int* ntiles_p = cursor + 125;          // 1
    int ub = (8 * E) / TM + 126;
    int* tile_k = ntiles_p + 1;
    int* tile_lo = tile_k + ub;
    float* sw = (float*)(tile_lo + ub);
    int* ssrc = (int*)(sw + (size_t)8 * E);
    int* sdst = ssrc + 8 * E;

    int nz = N * COUT + N + 125;  // zero agg + deg + hist in one shot (contiguous)
    fill_u32<<<(nz + 255) / 256, 256, 0, stream>>>((unsigned*)agg, nz, 0u);
    hist_deg_kernel<<<(E + 255) / 256, 256, 0, stream>>>(ps, dst, E, hist, deg);
    prefix_tiles<TM><<<1, 128, 0, stream>>>(hist, binstart, cursor, tile_k, tile_lo, ntiles_p);
    scatter_kernel<<<(E + 255) / 256, 256, 0, stream>>>(ps, src, dst, E, cursor, sw, ssrc, sdst);
    int grid = ub < 2048 ? ub : 2048;
    bin_gemm<CIN, COUT, TM><<<grid, 256, 0, stream>>>(x, W, sw, ssrc, sdst, tile_k, tile_lo,
                                                      binstart, ntiles_p, agg);
    int nf = N * COUT;
    conv_finish<CIN, COUT><<<(nf + 255) / 256, 256, 0, stream>>>(x, agg, deg, root, bias, y, N);
}

extern "C" void kernel_launch(void* const* d_in, const int* in_sizes, int n_in,
                              void* d_out, int out_size, void* d_ws, size_t ws_size,
                              hipStream_t stream) {
    const float* x0 = (const float*)d_in[0];
    const int* cl[6];
    for (int i = 0; i < 6; ++i) cl[i] = (const int*)d_in[1 + i];
    const int* src[5];
    const int* dst[5];
    const float* ps[5];
    const float* W[5];
    const float* root[5];
    const float* bias[5];
    for (int i = 0; i < 5; ++i) {
        src[i] = (const int*)d_in[7 + 6 * i];
        dst[i] = (const int*)d_in[8 + 6 * i];
        ps[i] = (const float*)d_in[9 + 6 * i];
        W[i] = (const float*)d_in[10 + 6 * i];
        root[i] = (const float*)d_in[11 + 6 * i];
        bias[i] = (const float*)d_in[12 + 6 * i];
    }
    const float* fc1_w = (const float*)d_in[37];
    const float* fc1_b = (const float*)d_in[38];
    const float* fc2_w = (const float*)d_in[39];
    const float* fc2_b = (const float*)d_in[40];

    float* ws = (float*)d_ws;
    float* xp1 = ws;              // 20000
    float* y1 = xp1 + 20000;      // 640000
    float* xp2 = y1 + 640000;     // 192000
    float* y2 = xp2 + 192000;     // 384000
    float* xp3 = y2 + 384000;     // 128000
    float* y3 = xp3 + 128000;     // 128000
    float* xp4 = y3 + 128000;     // 44800
    float* y4 = xp4 + 44800;      // 44800
    float* xp5 = y4 + 44800;      // 16384
    float* y5 = xp5 + 16384;      // 32768
    float* xp6 = y5 + 32768;      // 1024
    float* fc1o = xp6 + 1024;     // 512
    float* arena = fc1o + 512;    // per-stage scratch (~1.55M floats max)

    auto pool = [&](const float* xin, const int* c, float* xout, int n_in2, int n_out, int C) {
        unsigned* mono = (unsigned*)arena;
        int nmono = n_out * C;
        fill_u32<<<(nmono + 255) / 256, 256, 0, stream>>>(mono, nmono, 0u);
        int ns = n_in2 * C;
        pool_scatter<<<(ns + 255) / 256, 256, 0, stream>>>(xin, c, mono, n_in2, C);
        pool_final<<<(nmono + 255) / 256, 256, 0, stream>>>(mono, xout, nmono);
    };

    // level 1 (Cin=1): direct edge kernel
    pool(x0, cl[0], xp1, 80000, 20000, 1);
    {
        int N = 20000, E = 160000;
        float* agg = arena;
        float* deg = agg + (size_t)N * 32;
        int nz = N * 32 + N;
        fill_u32<<<(nz + 255) / 256, 256, 0, stream>>>((unsigned*)agg, nz, 0u);
        spline_edge_c1<<<(E * 32 + 255) / 256, 256, 0, stream>>>(xp1, src[0], dst[0], ps[0],
                                                                 W[0], agg, deg, E);
        int nf = N * 32;
        conv_finish<1, 32><<<(nf + 255) / 256, 256, 0, stream>>>(xp1, agg, deg, root[0], bias[0],
                                                                 y1, N);
    }
    // levels 2-5: binned GEMM path
    pool(y1, cl[1], xp2, 20000, 6000, 32);
    run_conv_binned<32, 64>(xp2, src[1], dst[1], ps[1], W[1], root[1], bias[1], y2, arena, 6000,
                            48000, stream);
    pool(y2, cl[2], xp3, 6000, 2000, 64);
    run_conv_binned<64, 64>(xp3, src[2], dst[2], ps[2], W[2], root[2], bias[2], y3, arena, 2000,
                            16000, stream);
    pool(y3, cl[3], xp4, 2000, 700, 64);
    run_conv_binned<64, 64>(xp4, src[3], dst[3], ps[3], W[3], root[3], bias[3], y4, arena, 700,
                            5600, stream);
    pool(y4, cl[4], xp5, 700, 256, 64);
    run_conv_binned<64, 128>(xp5, src[4], dst[4], ps[4], W[4], root[4], bias[4], y5, arena, 256,
                             2048, stream);
    // final dense pool to 8 nodes -> [1,1024]
    pool(y5, cl[5], xp6, 256, 8, 128);
    // FC head
    fc1_kernel<<<2, 256, 0, stream>>>(xp6, fc1_w, fc1_b, fc1o);
    fc2_lsm<<<1, 64, 0, stream>>>(fc1o, fc2_w, fc2_b, (float*)d_out);
}

// Round 3
// 472.632 us; speedup vs baseline: 1.7271x; 1.7271x over previous
//
#include <hip/hip_runtime.h>
#include <math.h>

#define DEVINL __device__ __forceinline__

// ---------------------------------------------------------------------------
// SplineCNN net. Round 2: atomic-free conv path.
//   k-binned GEMM -> streaming msgs[pos, Cout] -> dst-CSR gather aggregation.
// Global f32 atomics (393 MB/dispatch of 16B memory-side ops in round 1) were
// the bottleneck; only tiny int counting-sort atomics remain.
// ---------------------------------------------------------------------------

DEVINL unsigned f2mono(float f) {
    unsigned u = __float_as_uint(f);
    return (u & 0x80000000u) ? ~u : (u | 0x80000000u);
}
DEVINL float mono2f(unsigned m) {
    unsigned u = (m & 0x80000000u) ? (m & 0x7FFFFFFFu) : ~m;
    return __uint_as_float(u);
}

__global__ void fill_u32(unsigned* __restrict__ p, int n, unsigned v) {
    int i = blockIdx.x * blockDim.x + threadIdx.x;
    if (i < n) p[i] = v;
}

__global__ void pool_scatter(const float* __restrict__ x, const int* __restrict__ cl,
                             unsigned* __restrict__ mono, int n_in, int C) {
    int i = blockIdx.x * blockDim.x + threadIdx.x;
    if (i >= n_in * C) return;
    int node = i / C;
    int c = i - node * C;
    atomicMax(&mono[cl[node] * C + c], f2mono(x[i]));
}

__global__ void pool_final(const unsigned* __restrict__ mono, float* __restrict__ out, int n) {
    int i = blockIdx.x * blockDim.x + threadIdx.x;
    if (i < n) {
        unsigned m = mono[i];
        out[i] = (m == 0u) ? 0.f : mono2f(m);  // sentinel 0 == empty segment
    }
}

DEVINL void pseudo_decode(const float* __restrict__ ps, int e, int ff[3], float fr[3]) {
#pragma unroll
    for (int d = 0; d < 3; ++d) {
        float p = ps[(size_t)e * 3 + d] * 4.0f;  // (K-1) = 4
        float f = floorf(p);
        ff[d] = (int)f;
        fr[d] = p - f;
    }
}

DEVINL void corner_iw(const int ff[3], const float fr[3], int bits, float& w, int& idx) {
    w = 1.f;
    idx = 0;
    int pw = 1;
#pragma unroll
    for (int d = 0; d < 3; ++d) {
        int b = (bits >> d) & 1;
        w *= b ? fr[d] : (1.f - fr[d]);
        int fd = ff[d] + b;
        fd = fd < 0 ? 0 : (fd > 4 ? 4 : fd);
        idx += fd * pw;
        pw *= 5;
    }
}

// degree count (int) by dst
__global__ void deg_only(const int* __restrict__ dst, int E, int* __restrict__ deg) {
    int e = blockIdx.x * blockDim.x + threadIdx.x;
    if (e < E) atomicAdd(&deg[dst[e]], 1);
}

// exclusive scan of cnt[N] -> row[N+1]; also copies into cur[N]
DEVINL void scan_nodes_dev(const int* __restrict__ cnt, int N, int* __restrict__ row,
                           int* __restrict__ cur) {
    __shared__ int part[256];
    int t = threadIdx.x;
    int chunk = (N + 255) / 256;
    int lo = t * chunk, hi = min(lo + chunk, N);
    int s = 0;
    for (int i = lo; i < hi; ++i) s += cnt[i];
    part[t] = s;
    __syncthreads();
    if (t == 0) {
        int run = 0;
        for (int i = 0; i < 256; ++i) {
            int v = part[i];
            part[i] = run;
            run += v;
        }
        row[N] = run;
    }
    __syncthreads();
    int run = part[t];
    for (int i = lo; i < hi; ++i) {
        row[i] = run;
        cur[i] = run;
        run += cnt[i];
    }
}

__global__ void scan_nodes(const int* __restrict__ cnt, int N, int* __restrict__ row,
                           int* __restrict__ cur) {
    scan_nodes_dev(cnt, N, row, cur);
}

// counting-sort edges by dst
__global__ void scatter_dst(const int* __restrict__ dst, int E, int* __restrict__ ecur,
                            int* __restrict__ eperm) {
    int e = blockIdx.x * blockDim.x + threadIdx.x;
    if (e < E) eperm[atomicAdd(&ecur[dst[e]], 1)] = e;
}

// ---------------- binned path (levels 2-5), edge range [e0,e1) ----------------
__global__ void hist_kernel(const float* __restrict__ pseudo, const int* __restrict__ dst,
                            int e0, int e1, int* __restrict__ hist, int* __restrict__ ideg) {
    __shared__ int lh[125];
    int t = threadIdx.x;
    for (int i = t; i < 125; i += 256) lh[i] = 0;
    __syncthreads();
    int e = e0 + blockIdx.x * 256 + t;
    if (e < e1) {
        int ff[3];
        float fr[3];
        pseudo_decode(pseudo, e, ff, fr);
#pragma unroll
        for (int b = 0; b < 8; ++b) {
            float w;
            int idx;
            corner_iw(ff, fr, b, w, idx);
            atomicAdd(&lh[idx], 1);
        }
        atomicAdd(&ideg[dst[e]], 1);
    }
    __syncthreads();
    for (int i = t; i < 125; i += 256)
        if (lh[i]) atomicAdd(&hist[i], lh[i]);
}

// block 0: bin prefix + tile list; block 1: node-degree scan -> erow/ecursor
template <int TM>
__global__ void prep_kernel(const int* __restrict__ hist, int* __restrict__ binstart,
                            int* __restrict__ cursor, int* __restrict__ tile_k,
                            int* __restrict__ tile_lo, int* __restrict__ ntiles_p,
                            const int* __restrict__ ideg, int N, int* __restrict__ erow,
                            int* __restrict__ ecursor) {
    if (blockIdx.x == 1) {
        scan_nodes_dev(ideg, N, erow, ecursor);
        return;
    }
    __shared__ int bs[126], ts[126];
    int t = threadIdx.x;
    if (t == 0) {
        int run = 0, trun = 0;
        for (int k = 0; k < 125; ++k) {
            bs[k] = run;
            ts[k] = trun;
            run += hist[k];
            trun += (hist[k] + TM - 1) / TM;
        }
        bs[125] = run;
        ts[125] = trun;
        *ntiles_p = trun;
    }
    __syncthreads();
    if (t < 126) binstart[t] = bs[t];
    if (t < 125) {
        cursor[t] = bs[t];
        int nt = ts[t + 1] - ts[t];
        for (int j = 0; j < nt; ++j) {
            tile_k[ts[t] + j] = t;
            tile_lo[ts[t] + j] = bs[t] + j * TM;
        }
    }
}

__global__ void scatter_kernel(const float* __restrict__ pseudo, const int* __restrict__ src,
                               const int* __restrict__ dst, int e0, int e1,
                               int* __restrict__ cursor, int* __restrict__ ecursor,
                               float* __restrict__ sw, int* __restrict__ ssrc,
                               int* __restrict__ pos_eb, int* __restrict__ eperm) {
    __shared__ int lh[125], lbase[125];
    int t = threadIdx.x;
    for (int i = t; i < 125; i += 256) lh[i] = 0;
    __syncthreads();
    int e = e0 + blockIdx.x * 256 + t;
    int midx[8], mloc[8];
    float mw[8];
    if (e < e1) {
        int ff[3];
        float fr[3];
        pseudo_decode(pseudo, e, ff, fr);
#pragma unroll
        for (int b = 0; b < 8; ++b) {
            corner_iw(ff, fr, b, mw[b], midx[b]);
            mloc[b] = atomicAdd(&lh[midx[b]], 1);
        }
    }
    __syncthreads();
    for (int i = t; i < 125; i += 256) {
        int c = lh[i];
        lbase[i] = c ? atomicAdd(&cursor[i], c) : 0;
    }
    __syncthreads();
    if (e < e1) {
        int s = src[e];
#pragma unroll
        for (int b = 0; b < 8; ++b) {
            int pos = lbase[midx[b]] + mloc[b];
            sw[pos] = mw[b];
            ssrc[pos] = s;
            pos_eb[(size_t)(e - e0) * 8 + b] = pos;
        }
        eperm[atomicAdd(&ecursor[dst[e]], 1)] = e;
    }
}

// One 64-row tile of one bin per iteration: W_k in LDS (reused 64x), w-scaled x
// rows in LDS, register-tiled fp32 GEMM, STREAMING store to msgs[pos, COUT].
template <int CIN, int COUT, int TM>
__global__ __launch_bounds__(256) void bin_gemm(
    const float* __restrict__ x, const float* __restrict__ W, const float* __restrict__ sw,
    const int* __restrict__ ssrc, const int* __restrict__ tile_k, const int* __restrict__ tile_lo,
    const int* __restrict__ binstart, const int* __restrict__ ntiles_p,
    float* __restrict__ msgs) {
    constexpr int C4 = COUT / 4;
    constexpr int NTR = 256 / C4;
    constexpr int RT = TM / NTR;
    constexpr int XST = CIN + 4;
    constexpr int G = 256 / TM;
    __shared__ float Wl[CIN * COUT];
    __shared__ float xs[TM * XST];
    int t = threadIdx.x;
    int ntiles = *ntiles_p;
    int tc = t % C4, tr = t / C4;
    int rr = t / G, g = t % G;
    for (int tile = blockIdx.x; tile < ntiles; tile += gridDim.x) {
        int k = tile_k[tile];
        int lo = tile_lo[tile];
        int m = min(TM, binstart[k + 1] - lo);
        __syncthreads();
        {
            const float4* Wg = (const float4*)(W + (size_t)k * (CIN * COUT));
            float4* Wl4 = (float4*)Wl;
            for (int i = t; i < CIN * COUT / 4; i += 256) Wl4[i] = Wg[i];
        }
        if (rr < m) {
            int s = ssrc[lo + rr];
            float wv = sw[lo + rr];
            const float4* xr = (const float4*)(x + (size_t)s * CIN);
            float4* xd = (float4*)(xs + rr * XST);
#pragma unroll
            for (int i = g; i < CIN / 4; i += G) {
                float4 v = xr[i];
                v.x *= wv;
                v.y *= wv;
                v.z *= wv;
                v.w *= wv;
                xd[i] = v;
            }
        }
        __syncthreads();
        float4 acc[RT];
#pragma unroll
        for (int r = 0; r < RT; ++r) acc[r] = make_float4(0.f, 0.f, 0.f, 0.f);
#pragma unroll 4
        for (int i = 0; i < CIN; ++i) {
            float4 wv = ((const float4*)Wl)[i * C4 + tc];
#pragma unroll
            for (int r = 0; r < RT; ++r) {
                float xv = xs[(tr + r * NTR) * XST + i];
                acc[r].x += xv * wv.x;
                acc[r].y += xv * wv.y;
                acc[r].z += xv * wv.z;
                acc[r].w += xv * wv.w;
            }
        }
#pragma unroll
        for (int r = 0; r < RT; ++r) {
            int row = tr + r * NTR;
            if (row < m) ((float4*)(msgs + (size_t)(lo + row) * COUT))[tc] = acc[r];
        }
    }
}

// one wave per node: gather this node's 8*deg msg rows, sum, agg[d] += sum
template <int COUT>
__global__ __launch_bounds__(256) void aggregate(const float* __restrict__ msgs,
                                                 const int* __restrict__ erow,
                                                 const int* __restrict__ eperm,
                                                 const int* __restrict__ pos_eb, int e0,
                                                 float* __restrict__ agg, int N) {
    constexpr int CPL = COUT / 64;  // cols per lane
    int lane = threadIdx.x & 63;
    int wid = blockIdx.x * 4 + (threadIdx.x >> 6);
    int nw = gridDim.x * 4;
    for (int d = wid; d < N; d += nw) {
        float acc[CPL];
#pragma unroll
        for (int q = 0; q < CPL; ++q) acc[q] = 0.f;
        int lo = erow[d], hi = erow[d + 1];
        for (int j = lo; j < hi; ++j) {
            int p8 = (eperm[j] - e0) * 8;
#pragma unroll
            for (int b = 0; b < 8; ++b) {
                const float* mr = msgs + (size_t)pos_eb[p8 + b] * COUT;
#pragma unroll
                for (int q = 0; q < CPL; ++q) acc[q] += mr[lane + 64 * q];
            }
        }
        float* ap = agg + (size_t)d * COUT;
#pragma unroll
        for (int q = 0; q < CPL; ++q) ap[lane + 64 * q] += acc[q];
    }
}

// y = elu(agg/max(deg,1) + x@root + bias)
template <int CIN, int COUT>
__global__ void conv_finish(const float* __restrict__ x, const float* __restrict__ agg,
                            const int* __restrict__ deg, const float* __restrict__ root,
                            const float* __restrict__ bias, float* __restrict__ y, int N) {
    int tid = blockIdx.x * blockDim.x + threadIdx.x;
    if (tid >= N * COUT) return;
    int n = tid / COUT;
    int c = tid - n * COUT;
    float dv = (float)max(deg[n], 1);
    float v = agg[tid] / dv;
#pragma unroll
    for (int i = 0; i < CIN; ++i) v += x[(size_t)n * CIN + i] * root[(size_t)i * COUT + c];
    v += bias[c];
    y[tid] = v > 0.f ? v : expm1f(v);
}

// ---------------- level 1 (Cin=1, Cout=32): CSR + W1 in LDS, fully fused ------
__global__ __launch_bounds__(256) void l1_aggregate(
    const float* __restrict__ x, const float* __restrict__ ps, const int* __restrict__ src,
    const float* __restrict__ W, const int* __restrict__ erow, const int* __restrict__ eperm,
    const int* __restrict__ ideg, const float* __restrict__ root, const float* __restrict__ bias,
    float* __restrict__ y, int N) {
    __shared__ float Wl[125 * 32];
    int t = threadIdx.x;
    {
        const float4* Wg = (const float4*)W;
        float4* Wd = (float4*)Wl;
        for (int i = t; i < 125 * 32 / 4; i += 256) Wd[i] = Wg[i];
    }
    __syncthreads();
    int lane = t & 63, c = lane & 31, half = lane >> 5;
    int wid = blockIdx.x * 4 + (t >> 6);
    int nw = gridDim.x * 4;
    for (int d = wid; d < N; d += nw) {
        int lo = erow[d], hi = erow[d + 1];
        float acc = 0.f;
        for (int j = lo + half; j < hi; j += 2) {
            int e = eperm[j];
            int ff[3];
            float fr[3];
            pseudo_decode(ps, e, ff, fr);
            float wsum = 0.f;
#pragma unroll
            for (int b = 0; b < 8; ++b) {
                float w;
                int idx;
                corner_iw(ff, fr, b, w, idx);
                wsum += w * Wl[idx * 32 + c];
            }
            acc += x[src[e]] * wsum;
        }
        acc += __shfl_down(acc, 32);
        if (half == 0) {
            float dv = (float)max(ideg[d], 1);
            float v = acc / dv + x[d] * root[c] + bias[c];
            y[(size_t)d * 32 + c] = v > 0.f ? v : expm1f(v);
        }
    }
}

// fc1: [1024] @ [1024,512] + b, ELU
__global__ void fc1_kernel(const float* __restrict__ x, const float* __restrict__ w,
                           const float* __restrict__ b, float* __restrict__ out) {
    int o = blockIdx.x * blockDim.x + threadIdx.x;
    if (o >= 512) return;
    float acc = b[o];
#pragma unroll 8
    for (int i = 0; i < 1024; ++i) acc += x[i] * w[(size_t)i * 512 + o];
    out[o] = acc > 0.f ? acc : expm1f(acc);
}

__global__ void fc2_lsm(const float* __restrict__ x, const float* __restrict__ w,
                        const float* __restrict__ b, float* __restrict__ out) {
    __shared__ float z[10];
    int t = threadIdx.x;
    if (t < 10) {
        float acc = b[t];
        for (int i = 0; i < 512; ++i) acc += x[i] * w[(size_t)i * 10 + t];
        z[t] = acc;
    }
    __syncthreads();
    if (t == 0) {
        float m = z[0];
        for (int i = 1; i < 10; ++i) m = fmaxf(m, z[i]);
        float s = 0.f;
        for (int i = 0; i < 10; ++i) s += expf(z[i] - m);
        float l = logf(s);
        for (int i = 0; i < 10; ++i) out[i] = z[i] - m - l;
    }
}

// ---------------------------------------------------------------------------

template <int CIN, int COUT>
static void run_level(const float* x, const int* src, const int* dst, const float* ps,
                      const float* W, const float* root, const float* bias, float* y,
                      float* arena, size_t arenaWords, int N, int E, hipStream_t stream) {
    constexpr int TM = 64;
    size_t off = 0;
    float* agg = arena + off;
    off += (size_t)N * COUT;
    int* tdeg = (int*)(arena + off);
    off += N;
    int* hist = (int*)(arena + off);
    off += 125;
    int* ideg = (int*)(arena + off);
    off += N;
    int* binstart = (int*)(arena + off);
    off += 126;
    int* cursor = (int*)(arena + off);
    off += 125;
    int* ntiles_p = (int*)(arena + off);
    off += 1;
    int* erow = (int*)(arena + off);
    off += N + 1;
    int* ecursor = (int*)(arena + off);
    off += N;
    int* eperm = (int*)(arena + off);
    off += E;
    off = (off + 3) & ~(size_t)3;
    size_t fixedEnd = off;

    size_t avail = arenaWords > fixedEnd ? arenaWords - fixedEnd : 0;
    size_t perEntry = COUT + 4;  // msgs + pos_eb + ssrc + sw + tile slack
    size_t maxEntries = avail / perEntry;
    int Ec = (int)(maxEntries / 8);
    if (Ec > E) Ec = E;
    if (Ec < 256) Ec = 256;
    int nchunks = (E + Ec - 1) / Ec;

    if (nchunks == 1) {
        // zero agg + tdeg + hist + ideg in one shot (contiguous)
        int nz = N * COUT + N + 125 + N;
        fill_u32<<<(nz + 255) / 256, 256, 0, stream>>>((unsigned*)agg, nz, 0u);
    } else {
        int nz = N * COUT + N;
        fill_u32<<<(nz + 255) / 256, 256, 0, stream>>>((unsigned*)agg, nz, 0u);
        deg_only<<<(E + 255) / 256, 256, 0, stream>>>(dst, E, tdeg);
    }

    for (int c = 0; c < nchunks; ++c) {
        int e0 = c * Ec;
        int e1 = min(E, e0 + Ec);
        int ne = e1 - e0;
        int entries = 8 * ne;
        int ub = entries / TM + 126;
        size_t o = fixedEnd;
        int* pos_eb = (int*)(arena + o);
        o += entries;
        int* tile_k = (int*)(arena + o);
        o += ub;
        int* tile_lo = (int*)(arena + o);
        o += ub;
        int* ssrc = (int*)(arena + o);
        o += entries;
        float* sw = arena + o;
        o += entries;
        o = (o + 3) & ~(size_t)3;
        float* msgs = arena + o;

        if (nchunks > 1) {  // re-zero hist + ideg per chunk (contiguous)
            fill_u32<<<(125 + N + 255) / 256, 256, 0, stream>>>((unsigned*)hist, 125 + N, 0u);
        }
        hist_kernel<<<(ne + 255) / 256, 256, 0, stream>>>(ps, dst, e0, e1, hist, ideg);
        prep_kernel<TM><<<2, 256, 0, stream>>>(hist, binstart, cursor, tile_k, tile_lo, ntiles_p,
                                               ideg, N, erow, ecursor);
        scatter_kernel<<<(ne + 255) / 256, 256, 0, stream>>>(ps, src, dst, e0, e1, cursor, ecursor,
                                                             sw, ssrc, pos_eb, eperm);
        int grid = ub < 2048 ? ub : 2048;
        bin_gemm<CIN, COUT, TM><<<grid, 256, 0, stream>>>(x, W, sw, ssrc, tile_k, tile_lo,
                                                          binstart, ntiles_p, msgs);
        int agrid = (N + 3) / 4;
        if (agrid > 2048) agrid = 2048;
        aggregate<COUT><<<agrid, 256, 0, stream>>>(msgs, erow, eperm, pos_eb, e0, agg, N);
    }
    const int* degp = (nchunks > 1) ? tdeg : ideg;
    int nf = N * COUT;
    conv_finish<CIN, COUT><<<(nf + 255) / 256, 256, 0, stream>>>(x, agg, degp, root, bias, y, N);
}

extern "C" void kernel_launch(void* const* d_in, const int* in_sizes, int n_in,
                              void* d_out, int out_size, void* d_ws, size_t ws_size,
                              hipStream_t stream) {
    const float* x0 = (const float*)d_in[0];
    const int* cl[6];
    for (int i = 0; i < 6; ++i) cl[i] = (const int*)d_in[1 + i];
    const int* src[5];
    const int* dst[5];
    const float* ps[5];
    const float* W[5];
    const float* root[5];
    const float* bias[5];
    for (int i = 0; i < 5; ++i) {
        src[i] = (const int*)d_in[7 + 6 * i];
        dst[i] = (const int*)d_in[8 + 6 * i];
        ps[i] = (const float*)d_in[9 + 6 * i];
        W[i] = (const float*)d_in[10 + 6 * i];
        root[i] = (const float*)d_in[11 + 6 * i];
        bias[i] = (const float*)d_in[12 + 6 * i];
    }
    const float* fc1_w = (const float*)d_in[37];
    const float* fc1_b = (const float*)d_in[38];
    const float* fc2_w = (const float*)d_in[39];
    const float* fc2_b = (const float*)d_in[40];

    float* ws = (float*)d_ws;
    float* xp1 = ws;              // 20000
    float* y1 = xp1 + 20000;      // 640000
    float* xp2 = y1 + 640000;     // 192000
    float* y2 = xp2 + 192000;     // 384000
    float* xp3 = y2 + 384000;     // 128000
    float* y3 = xp3 + 128000;     // 128000
    float* xp4 = y3 + 128000;     // 44800
    float* y4 = xp4 + 44800;      // 44800
    float* xp5 = y4 + 44800;      // 16384
    float* y5 = xp5 + 16384;      // 32768
    float* xp6 = y5 + 32768;      // 1024
    float* fc1o = xp6 + 1024;     // 512
    float* arena = fc1o + 512;
    size_t persistent = (size_t)(arena - ws);
    size_t arenaWords = (ws_size / 4 > persistent) ? (ws_size / 4 - persistent) : 0;

    auto pool = [&](const float* xin, const int* c, float* xout, int n_in2, int n_out, int C) {
        unsigned* mono = (unsigned*)arena;
        int nmono = n_out * C;
        fill_u32<<<(nmono + 255) / 256, 256, 0, stream>>>(mono, nmono, 0u);
        int nsc = n_in2 * C;
        pool_scatter<<<(nsc + 255) / 256, 256, 0, stream>>>(xin, c, mono, n_in2, C);
        pool_final<<<(nmono + 255) / 256, 256, 0, stream>>>(mono, xout, nmono);
    };

    // ---- level 1 (Cin=1): dst-CSR + LDS-resident W1, fused finish ----
    pool(x0, cl[0], xp1, 80000, 20000, 1);
    {
        int N = 20000, E = 160000;
        size_t off = 0;
        int* ideg = (int*)(arena + off);
        off += N;
        int* erow = (int*)(arena + off);
        off += N + 1;
        int* ecur = (int*)(arena + off);
        off += N;
        int* eperm = (int*)(arena + off);
        fill_u32<<<(N + 255) / 256, 256, 0, stream>>>((unsigned*)ideg, N, 0u);
        deg_only<<<(E + 255) / 256, 256, 0, stream>>>(dst[0], E, ideg);
        scan_nodes<<<1, 256, 0, stream>>>(ideg, N, erow, ecur);
        scatter_dst<<<(E + 255) / 256, 256, 0, stream>>>(dst[0], E, ecur, eperm);
        int grid = (N + 3) / 4;
        if (grid > 2048) grid = 2048;
        l1_aggregate<<<grid, 256, 0, stream>>>(xp1, ps[0], src[0], W[0], erow, eperm, ideg,
                                               root[0], bias[0], y1, N);
    }
    // ---- levels 2-5: binned GEMM + streaming msgs + CSR gather ----
    pool(y1, cl[1], xp2, 20000, 6000, 32);
    run_level<32, 64>(xp2, src[1], dst[1], ps[1], W[1], root[1], bias[1], y2, arena, arenaWords,
                      6000, 48000, stream);
    pool(y2, cl[2], xp3, 6000, 2000, 64);
    run_level<64, 64>(xp3, src[2], dst[2], ps[2], W[2], root[2], bias[2], y3, arena, arenaWords,
                      2000, 16000, stream);
    pool(y3, cl[3], xp4, 2000, 700, 64);
    run_level<64, 64>(xp4, src[3], dst[3], ps[3], W[3], root[3], bias[3], y4, arena, arenaWords,
                      700, 5600, stream);
    pool(y4, cl[4], xp5, 700, 256, 64);
    run_level<64, 128>(xp5, src[4], dst[4], ps[4], W[4], root[4], bias[4], y5, arena, arenaWords,
                       256, 2048, stream);
    // final dense pool to 8 nodes -> [1,1024]
    pool(y5, cl[5], xp6, 256, 8, 128);
    // FC head
    fc1_kernel<<<2, 256, 0, stream>>>(xp6, fc1_w, fc1_b, fc1o);
    fc2_lsm<<<1, 64, 0, stream>>>(fc1o, fc2_w, fc2_b, (float*)d_out);
}